// Round 6
// baseline (947.633 us; speedup 1.0000x reference)
//
#include <hip/hip_runtime.h>
#include <math.h>

namespace {
constexpr int   NG    = 64;
constexpr int   GC    = NG * NG * NG;
constexpr int   BOUND = 3;
constexpr int   TPA   = 16;              // tiles per axis (4^3 cells per tile)
constexpr int   NT    = TPA * TPA * TPA; // 4096 tiles
constexpr int   TCELLS = 6 * 6 * 6;      // 216 halo cells per tile
constexpr float DXf    = 1.0f / 64.0f;
constexpr float INV_DX = 64.0f;
constexpr float DTf    = 5e-4f;
constexpr double P_VOL_D = (0.5 / 64.0) * (0.5 / 64.0) * (0.5 / 64.0);
constexpr float P_MASS_F = (float)(P_VOL_D * 1000.0);
constexpr float AFFINE_SCALE = (float)(-5e-4 * P_VOL_D * 4.0 * 64.0 * 64.0);
constexpr float D_INV  = 4.0f * 64.0f * 64.0f;   // 16384
constexpr float GRAV_Y = -9.8f;

__device__ __forceinline__ void atom_add_f32(float* p, float v) {
    unsafeAtomicAdd(p, v);   // hw ds_add_f32 / global_atomic_add_f32
}

__device__ __forceinline__ int tile_of(int b0, int b1, int b2) {
    return ((b0 >> 2) * TPA + (b1 >> 2)) * TPA + (b2 >> 2);
}
__device__ __forceinline__ void base_of(const float* x, int p,
                                        int& b0, int& b1, int& b2) {
    float t0 = x[3*p] * INV_DX, t1 = x[3*p+1] * INV_DX, t2 = x[3*p+2] * INV_DX;
    b0 = (int)floorf(t0 - 0.5f); b1 = (int)floorf(t1 - 0.5f); b2 = (int)floorf(t2 - 0.5f);
}

__device__ __forceinline__ void weights_of(float fx0, float fx1, float fx2, float w[3][3]) {
    w[0][0] = 0.5f*(1.5f-fx0)*(1.5f-fx0); w[0][1] = 0.5f*(1.5f-fx1)*(1.5f-fx1); w[0][2] = 0.5f*(1.5f-fx2)*(1.5f-fx2);
    w[1][0] = 0.75f-(fx0-1.0f)*(fx0-1.0f); w[1][1] = 0.75f-(fx1-1.0f)*(fx1-1.0f); w[1][2] = 0.75f-(fx2-1.0f)*(fx2-1.0f);
    w[2][0] = 0.5f*(fx0-0.5f)*(fx0-0.5f); w[2][1] = 0.5f*(fx1-0.5f)*(fx1-0.5f); w[2][2] = 0.5f*(fx2-0.5f)*(fx2-0.5f);
}
}

// ---------------- pass 1: histogram particles into tiles ----------------
__global__ __launch_bounds__(256) void count_kernel(const float* __restrict__ x,
                                                    int* __restrict__ cnt, int n)
{
    int p = blockIdx.x * 256 + threadIdx.x;
    if (p >= n) return;
    int b0, b1, b2; base_of(x, p, b0, b1, b2);
    atomicAdd(&cnt[tile_of(b0, b1, b2)], 1);
}

// ---------------- pass 2: exclusive scan over 4096 tile counts ----------------
__global__ __launch_bounds__(256) void scan_kernel(const int* __restrict__ cnt,
                                                   int* __restrict__ start,
                                                   int* __restrict__ cursor)
{
    __shared__ int partial[256];
    int tid = threadIdx.x;
    int local[16];
    int s = 0;
#pragma unroll
    for (int i = 0; i < 16; ++i) { local[i] = s; s += cnt[tid * 16 + i]; }
    partial[tid] = s;
    __syncthreads();
    for (int off = 1; off < 256; off <<= 1) {
        int v = (tid >= off) ? partial[tid - off] : 0;
        __syncthreads();
        partial[tid] += v;
        __syncthreads();
    }
    int base = (tid > 0) ? partial[tid - 1] : 0;
#pragma unroll
    for (int i = 0; i < 16; ++i) {
        int st = base + local[i];
        start[tid * 16 + i]  = st;
        cursor[tid * 16 + i] = st;
    }
}

// ---------------- pass 3: reorder — coalesced read, precompute, scattered payload write
// payload record (64B): [aff00..aff22, mv0..2, fx0..2, packed l-bits]
__global__ __launch_bounds__(256) void reorder_kernel(const float* __restrict__ x,
                                                      const float* __restrict__ v,
                                                      const float* __restrict__ C,
                                                      const float* __restrict__ st,
                                                      int* __restrict__ cursor,
                                                      float4* __restrict__ payload, int n)
{
    int p = blockIdx.x * 256 + threadIdx.x;
    if (p >= n) return;

    float xp0 = x[3*p], xp1 = x[3*p+1], xp2 = x[3*p+2];
    float u0 = xp0 * INV_DX, u1 = xp1 * INV_DX, u2 = xp2 * INV_DX;
    float b0f = floorf(u0 - 0.5f), b1f = floorf(u1 - 0.5f), b2f = floorf(u2 - 0.5f);
    int b0 = (int)b0f, b1 = (int)b1f, b2 = (int)b2f;
    float fx0 = u0 - b0f, fx1 = u1 - b1f, fx2 = u2 - b2f;

    float aff[9];
#pragma unroll
    for (int i = 0; i < 9; ++i)
        aff[i] = st[9*p + i] * AFFINE_SCALE + P_MASS_F * C[9*p + i];
    float mv0 = P_MASS_F * v[3*p], mv1 = P_MASS_F * v[3*p+1], mv2 = P_MASS_F * v[3*p+2];

    int pos = atomicAdd(&cursor[tile_of(b0, b1, b2)], 1);
    int bits = (b0 & 3) | ((b1 & 3) << 2) | ((b2 & 3) << 4);

    float4* dst = payload + 4 * (size_t)pos;
    dst[0] = make_float4(aff[0], aff[1], aff[2], aff[3]);
    dst[1] = make_float4(aff[4], aff[5], aff[6], aff[7]);
    dst[2] = make_float4(aff[8], mv0, mv1, mv2);
    dst[3] = make_float4(fx0, fx1, fx2, __int_as_float(bits));
}

// ---------------- pass 4: tiled P2G, coalesced payload load + SoA LDS ----------------
__global__ __launch_bounds__(256) void p2g_tiled(const float4* __restrict__ payload,
                                                 const int* __restrict__ start,
                                                 const int* __restrict__ cnt,
                                                 float* __restrict__ grid)
{
    int t = blockIdx.x;
    int n = cnt[t];
    if (n == 0) return;

    __shared__ float lg[4 * TCELLS];
    for (int i = threadIdx.x; i < 4 * TCELLS; i += 256) lg[i] = 0.f;
    __syncthreads();

    int t0 = t / (TPA * TPA), t1 = (t / TPA) % TPA, t2 = t % TPA;
    int org0 = t0 * 4, org1 = t1 * 4, org2 = t2 * 4;
    int s0 = start[t];

    for (int i = threadIdx.x; i < n; i += 256) {
        const float4* src = payload + 4 * (size_t)(s0 + i);
        float4 a0 = src[0], a1 = src[1], a2 = src[2], a3 = src[3];

        float fx0 = a3.x, fx1 = a3.y, fx2 = a3.z;
        int bits = __float_as_int(a3.w);
        int l0 = bits & 3, l1 = (bits >> 2) & 3, l2 = (bits >> 4) & 3;

        float w[3][3];
        weights_of(fx0, fx1, fx2, w);

        // aff rows: [a0.x a0.y a0.z; a0.w a1.x a1.y; a1.z a1.w a2.x]
        float af00 = a0.x, af01 = a0.y, af02 = a0.z;
        float af10 = a0.w, af11 = a1.x, af12 = a1.y;
        float af20 = a1.z, af21 = a1.w, af22 = a2.x;
        float mv0 = a2.y, mv1 = a2.z, mv2 = a2.w;

#pragma unroll
        for (int oi = 0; oi < 3; ++oi) {
            float dp0 = ((float)oi - fx0) * DXf;
#pragma unroll
            for (int oj = 0; oj < 3; ++oj) {
                float dp1 = ((float)oj - fx1) * DXf;
                float wij = w[oi][0] * w[oj][1];
                float m0 = mv0 + af00*dp0 + af01*dp1;
                float m1 = mv1 + af10*dp0 + af11*dp1;
                float m2 = mv2 + af20*dp0 + af21*dp1;
                int lij = (((l0 + oi) * 6) + (l1 + oj)) * 6 + l2;
#pragma unroll
                for (int ok = 0; ok < 3; ++ok) {
                    float dp2 = ((float)ok - fx2) * DXf;
                    float wi = wij * w[ok][2];
                    int cell = lij + ok;
                    atom_add_f32(&lg[0 * TCELLS + cell], wi * (m0 + af02*dp2));
                    atom_add_f32(&lg[1 * TCELLS + cell], wi * (m1 + af12*dp2));
                    atom_add_f32(&lg[2 * TCELLS + cell], wi * (m2 + af22*dp2));
                    atom_add_f32(&lg[3 * TCELLS + cell], wi * P_MASS_F);
                }
            }
        }
    }
    __syncthreads();

    for (int c = threadIdx.x; c < TCELLS; c += 256) {
        int c0 = c / 36, c1 = (c / 6) % 6, c2 = c % 6;
        int g0 = org0 + c0, g1 = org1 + c1, g2 = org2 + c2;
        if (g0 >= NG || g1 >= NG || g2 >= NG) continue;
        float a0 = lg[0 * TCELLS + c], a1 = lg[1 * TCELLS + c];
        float a2 = lg[2 * TCELLS + c], a3 = lg[3 * TCELLS + c];
        if (a3 == 0.f && a0 == 0.f && a1 == 0.f && a2 == 0.f) continue;
        float* gptr = grid + 4 * (((g0 * NG) + g1) * NG + g2);
        atom_add_f32(gptr + 0, a0);
        atom_add_f32(gptr + 1, a1);
        atom_add_f32(gptr + 2, a2);
        atom_add_f32(gptr + 3, a3);
    }
}

// ---------------- fallback P2G: direct global atomics ----------------
__global__ __launch_bounds__(256) void p2g_naive(const float* __restrict__ x,
                                                 const float* __restrict__ v,
                                                 const float* __restrict__ C,
                                                 const float* __restrict__ st,
                                                 float* __restrict__ grid, int n)
{
    int p = blockIdx.x * 256 + threadIdx.x;
    if (p >= n) return;

    float xp0 = x[3*p], xp1 = x[3*p+1], xp2 = x[3*p+2];
    float u0 = xp0 * INV_DX, u1 = xp1 * INV_DX, u2 = xp2 * INV_DX;
    float b0f = floorf(u0 - 0.5f), b1f = floorf(u1 - 0.5f), b2f = floorf(u2 - 0.5f);
    int base0 = (int)b0f, base1 = (int)b1f, base2 = (int)b2f;
    float fx0 = u0 - b0f, fx1 = u1 - b1f, fx2 = u2 - b2f;

    float w[3][3];
    weights_of(fx0, fx1, fx2, w);

    float aff[3][3];
#pragma unroll
    for (int i = 0; i < 3; ++i)
#pragma unroll
        for (int j = 0; j < 3; ++j)
            aff[i][j] = st[9*p + 3*i + j] * AFFINE_SCALE + P_MASS_F * C[9*p + 3*i + j];

    float mv0 = P_MASS_F * v[3*p], mv1 = P_MASS_F * v[3*p+1], mv2 = P_MASS_F * v[3*p+2];

#pragma unroll
    for (int i = 0; i < 3; ++i) {
        float dp0 = ((float)i - fx0) * DXf;
#pragma unroll
        for (int j = 0; j < 3; ++j) {
            float dp1 = ((float)j - fx1) * DXf;
            float wij = w[i][0] * w[j][1];
            float m0 = mv0 + aff[0][0]*dp0 + aff[0][1]*dp1;
            float m1 = mv1 + aff[1][0]*dp0 + aff[1][1]*dp1;
            float m2 = mv2 + aff[2][0]*dp0 + aff[2][1]*dp1;
            int cellij = ((base0 + i) * NG + (base1 + j)) * NG + base2;
#pragma unroll
            for (int k = 0; k < 3; ++k) {
                float dp2 = ((float)k - fx2) * DXf;
                float wi = wij * w[k][2];
                float* cptr = grid + 4 * (cellij + k);
                atom_add_f32(cptr + 0, wi * (m0 + aff[0][2]*dp2));
                atom_add_f32(cptr + 1, wi * (m1 + aff[1][2]*dp2));
                atom_add_f32(cptr + 2, wi * (m2 + aff[2][2]*dp2));
                atom_add_f32(cptr + 3, wi * P_MASS_F);
            }
        }
    }
}

// ---------------- grid: normalize, gravity, boundary ----------------
__global__ __launch_bounds__(256) void grid_kernel(float* __restrict__ grid)
{
    int g = blockIdx.x * 256 + threadIdx.x;
    if (g >= GC) return;
    float4 val = ((const float4*)grid)[g];
    float m = val.w;
    float v0 = 0.f, v1 = 0.f, v2 = 0.f;
    if (m > 0.f) {
        float mm = fmaxf(m, 1e-10f);
        v0 = val.x / mm;
        v1 = val.y / mm + DTf * GRAV_Y;
        v2 = val.z / mm;
    }
    int ci = g >> 12, cj = (g >> 6) & 63, ck = g & 63;
    if ((ci < BOUND && v0 < 0.f) || (ci >= NG - BOUND && v0 > 0.f)) v0 = 0.f;
    if ((cj < BOUND && v1 < 0.f) || (cj >= NG - BOUND && v1 > 0.f)) v1 = 0.f;
    if ((ck < BOUND && v2 < 0.f) || (ck >= NG - BOUND && v2 > 0.f)) v2 = 0.f;
    ((float4*)grid)[g] = make_float4(v0, v1, v2, m);
}

// ---------------- G2P: gather, advect, update C/F ----------------
__global__ __launch_bounds__(256) void g2p_kernel(const float* __restrict__ x,
                                                  const float* __restrict__ F,
                                                  const float* __restrict__ grid,
                                                  float* __restrict__ out_x,
                                                  float* __restrict__ out_v,
                                                  float* __restrict__ out_C,
                                                  float* __restrict__ out_F,
                                                  int n)
{
    int p = blockIdx.x * 256 + threadIdx.x;
    if (p >= n) return;

    float xp0 = x[3*p], xp1 = x[3*p+1], xp2 = x[3*p+2];
    float t0 = xp0 * INV_DX, t1 = xp1 * INV_DX, t2 = xp2 * INV_DX;
    float b0 = floorf(t0 - 0.5f), b1 = floorf(t1 - 0.5f), b2 = floorf(t2 - 0.5f);
    int   base0 = (int)b0, base1 = (int)b1, base2 = (int)b2;
    float fx0 = t0 - b0, fx1 = t1 - b1, fx2 = t2 - b2;

    float w[3][3];
    weights_of(fx0, fx1, fx2, w);

    float vn0 = 0.f, vn1 = 0.f, vn2 = 0.f;
    float Cn[3][3] = {};

#pragma unroll
    for (int i = 0; i < 3; ++i) {
        float dp0 = ((float)i - fx0) * DXf;
#pragma unroll
        for (int j = 0; j < 3; ++j) {
            float dp1 = ((float)j - fx1) * DXf;
            float wij = w[i][0] * w[j][1];
            int cellij = ((base0 + i) * NG + (base1 + j)) * NG + base2;
#pragma unroll
            for (int k = 0; k < 3; ++k) {
                float dp2 = ((float)k - fx2) * DXf;
                float wi = wij * w[k][2];
                float4 gv = ((const float4*)grid)[cellij + k];
                vn0 += wi * gv.x; vn1 += wi * gv.y; vn2 += wi * gv.z;
                float wx = wi * gv.x, wy = wi * gv.y, wz = wi * gv.z;
                Cn[0][0] += wx * dp0; Cn[0][1] += wx * dp1; Cn[0][2] += wx * dp2;
                Cn[1][0] += wy * dp0; Cn[1][1] += wy * dp1; Cn[1][2] += wy * dp2;
                Cn[2][0] += wz * dp0; Cn[2][1] += wz * dp1; Cn[2][2] += wz * dp2;
            }
        }
    }

#pragma unroll
    for (int i = 0; i < 3; ++i)
#pragma unroll
        for (int j = 0; j < 3; ++j)
            Cn[i][j] *= D_INV;

    out_x[3*p]   = xp0 + DTf * vn0;
    out_x[3*p+1] = xp1 + DTf * vn1;
    out_x[3*p+2] = xp2 + DTf * vn2;
    out_v[3*p]   = vn0; out_v[3*p+1] = vn1; out_v[3*p+2] = vn2;

    float Fp[3][3];
#pragma unroll
    for (int i = 0; i < 3; ++i)
#pragma unroll
        for (int j = 0; j < 3; ++j)
            Fp[i][j] = F[9*p + 3*i + j];

#pragma unroll
    for (int i = 0; i < 3; ++i) {
#pragma unroll
        for (int k = 0; k < 3; ++k) {
            float acc = Cn[i][0]*Fp[0][k] + Cn[i][1]*Fp[1][k] + Cn[i][2]*Fp[2][k];
            out_F[9*p + 3*i + k] = Fp[i][k] + DTf * acc;
            out_C[9*p + 3*i + k] = Cn[i][k];
        }
    }
}

extern "C" void kernel_launch(void* const* d_in, const int* in_sizes, int n_in,
                              void* d_out, int out_size, void* d_ws, size_t ws_size,
                              hipStream_t stream)
{
    const float* x  = (const float*)d_in[0];
    const float* v  = (const float*)d_in[1];
    const float* C  = (const float*)d_in[2];
    const float* F  = (const float*)d_in[3];
    const float* st = (const float*)d_in[4];
    int n = in_sizes[0] / 3;

    const size_t grid_bytes = (size_t)GC * 4 * sizeof(float);          // 4 MiB
    const size_t tab_bytes  = (size_t)NT * 3 * sizeof(int);            // 48 KiB
    const bool   use_tiled  = ws_size >= grid_bytes + tab_bytes &&
                              (size_t)out_size >= 22 * (size_t)n;      // payload fits in out[6n..22n]

    char* ws = (char*)d_ws;
    float* grid = (float*)ws;  ws += grid_bytes;
    int* cnt    = (int*)ws;    ws += NT * sizeof(int);
    int* tstart = (int*)ws;    ws += NT * sizeof(int);
    int* cursor = (int*)ws;    ws += NT * sizeof(int);

    float* out  = (float*)d_out;
    float* out_x = out;
    float* out_v = out + 3 * (size_t)n;
    float* out_C = out + 6 * (size_t)n;
    float* out_F = out + 15 * (size_t)n;
    // payload (16 floats/particle) lives in out[6n .. 22n) — dead until g2p overwrites
    float4* payload = (float4*)(out + 6 * (size_t)n);

    int pblocks = (n + 255) / 256;

    if (use_tiled) {
        // grid and cnt are contiguous -> single memset
        hipMemsetAsync(grid, 0, grid_bytes + NT * sizeof(int), stream);
        count_kernel<<<pblocks, 256, 0, stream>>>(x, cnt, n);
        scan_kernel<<<1, 256, 0, stream>>>(cnt, tstart, cursor);
        reorder_kernel<<<pblocks, 256, 0, stream>>>(x, v, C, st, cursor, payload, n);
        p2g_tiled<<<NT, 256, 0, stream>>>(payload, tstart, cnt, grid);
    } else {
        hipMemsetAsync(grid, 0, grid_bytes, stream);
        p2g_naive<<<pblocks, 256, 0, stream>>>(x, v, C, st, grid, n);
    }

    grid_kernel<<<GC / 256, 256, 0, stream>>>(grid);
    g2p_kernel<<<pblocks, 256, 0, stream>>>(x, F, grid, out_x, out_v, out_C, out_F, n);
}

// Round 7
// 729.445 us; speedup vs baseline: 1.2991x; 1.2991x over previous
//
#include <hip/hip_runtime.h>
#include <math.h>

namespace {
constexpr int   NG    = 64;
constexpr int   GC    = NG * NG * NG;
constexpr int   BOUND = 3;
constexpr int   TPA   = 16;              // tiles per axis (4^3 cells per tile)
constexpr int   NT    = TPA * TPA * TPA; // 4096 tiles
constexpr float DXf    = 1.0f / 64.0f;
constexpr float INV_DX = 64.0f;
constexpr float DTf    = 5e-4f;
constexpr double P_VOL_D = (0.5 / 64.0) * (0.5 / 64.0) * (0.5 / 64.0);
constexpr float P_MASS_F = (float)(P_VOL_D * 1000.0);
constexpr float AFFINE_SCALE = (float)(-5e-4 * P_VOL_D * 4.0 * 64.0 * 64.0);
constexpr float D_INV  = 4.0f * 64.0f * 64.0f;   // 16384
constexpr float GRAV_Y = -9.8f;

__device__ __forceinline__ void atom_add_f32(float* p, float v) {
    unsafeAtomicAdd(p, v);   // hw global_atomic_add_f32, fire-and-forget
}

__device__ __forceinline__ int tile_of(int b0, int b1, int b2) {
    return ((b0 >> 2) * TPA + (b1 >> 2)) * TPA + (b2 >> 2);
}
__device__ __forceinline__ void base_of(const float* x, int p,
                                        int& b0, int& b1, int& b2) {
    float t0 = x[3*p] * INV_DX, t1 = x[3*p+1] * INV_DX, t2 = x[3*p+2] * INV_DX;
    b0 = (int)floorf(t0 - 0.5f); b1 = (int)floorf(t1 - 0.5f); b2 = (int)floorf(t2 - 0.5f);
}

__device__ __forceinline__ void weights_of(float fx0, float fx1, float fx2, float w[3][3]) {
    w[0][0] = 0.5f*(1.5f-fx0)*(1.5f-fx0); w[0][1] = 0.5f*(1.5f-fx1)*(1.5f-fx1); w[0][2] = 0.5f*(1.5f-fx2)*(1.5f-fx2);
    w[1][0] = 0.75f-(fx0-1.0f)*(fx0-1.0f); w[1][1] = 0.75f-(fx1-1.0f)*(fx1-1.0f); w[1][2] = 0.75f-(fx2-1.0f)*(fx2-1.0f);
    w[2][0] = 0.5f*(fx0-0.5f)*(fx0-0.5f); w[2][1] = 0.5f*(fx1-0.5f)*(fx1-0.5f); w[2][2] = 0.5f*(fx2-0.5f)*(fx2-0.5f);
}

// quadratic B-spline weight at signed offset u = fx - d; 0 outside |u|<1.5
__device__ __forceinline__ float bspline_w(float u) {
    float au = fabsf(u);
    float a  = 1.5f - au;
    float w  = (au < 0.5f) ? (0.75f - u * u) : (0.5f * a * a);
    return (au < 1.5f) ? w : 0.f;
}
}

// ---------------- pass 1: histogram particles into tiles ----------------
__global__ __launch_bounds__(256) void count_kernel(const float* __restrict__ x,
                                                    int* __restrict__ cnt, int n)
{
    int p = blockIdx.x * 256 + threadIdx.x;
    if (p >= n) return;
    int b0, b1, b2; base_of(x, p, b0, b1, b2);
    atomicAdd(&cnt[tile_of(b0, b1, b2)], 1);
}

// ---------------- pass 2: exclusive scan over 4096 tile counts ----------------
__global__ __launch_bounds__(256) void scan_kernel(const int* __restrict__ cnt,
                                                   int* __restrict__ start,
                                                   int* __restrict__ cursor)
{
    __shared__ int partial[256];
    int tid = threadIdx.x;
    int local[16];
    int s = 0;
#pragma unroll
    for (int i = 0; i < 16; ++i) { local[i] = s; s += cnt[tid * 16 + i]; }
    partial[tid] = s;
    __syncthreads();
    for (int off = 1; off < 256; off <<= 1) {
        int v = (tid >= off) ? partial[tid - off] : 0;
        __syncthreads();
        partial[tid] += v;
        __syncthreads();
    }
    int base = (tid > 0) ? partial[tid - 1] : 0;
#pragma unroll
    for (int i = 0; i < 16; ++i) {
        int st = base + local[i];
        start[tid * 16 + i]  = st;
        cursor[tid * 16 + i] = st;
    }
}

// ---------------- pass 3: reorder — coalesced read, precompute, payload write
// payload record (64B): [af00,af01,af02,af10][af11,af12,af20,af21][af22,mv0,mv1,mv2][fx0,fx1,fx2,lbits]
__global__ __launch_bounds__(256) void reorder_kernel(const float* __restrict__ x,
                                                      const float* __restrict__ v,
                                                      const float* __restrict__ C,
                                                      const float* __restrict__ st,
                                                      int* __restrict__ cursor,
                                                      float4* __restrict__ payload, int n)
{
    int p = blockIdx.x * 256 + threadIdx.x;
    if (p >= n) return;

    float xp0 = x[3*p], xp1 = x[3*p+1], xp2 = x[3*p+2];
    float u0 = xp0 * INV_DX, u1 = xp1 * INV_DX, u2 = xp2 * INV_DX;
    float b0f = floorf(u0 - 0.5f), b1f = floorf(u1 - 0.5f), b2f = floorf(u2 - 0.5f);
    int b0 = (int)b0f, b1 = (int)b1f, b2 = (int)b2f;
    float fx0 = u0 - b0f, fx1 = u1 - b1f, fx2 = u2 - b2f;

    float aff[9];
#pragma unroll
    for (int i = 0; i < 9; ++i)
        aff[i] = st[9*p + i] * AFFINE_SCALE + P_MASS_F * C[9*p + i];
    float mv0 = P_MASS_F * v[3*p], mv1 = P_MASS_F * v[3*p+1], mv2 = P_MASS_F * v[3*p+2];

    int pos = atomicAdd(&cursor[tile_of(b0, b1, b2)], 1);
    int bits = (b0 & 3) | ((b1 & 3) << 2) | ((b2 & 3) << 4);

    float4* dst = payload + 4 * (size_t)pos;
    dst[0] = make_float4(aff[0], aff[1], aff[2], aff[3]);
    dst[1] = make_float4(aff[4], aff[5], aff[6], aff[7]);
    dst[2] = make_float4(aff[8], mv0, mv1, mv2);
    dst[3] = make_float4(fx0, fx1, fx2, __int_as_float(bits));
}

// ---------------- pass 4: cell-centric gather P2G — NO atomics in hot loop ----
// one wave (64 thr) per tile; lane < 36 owns column (c0,c1) of the 6^3 halo,
// accumulates its 6 cells x 4 components in registers.
__global__ __launch_bounds__(64) void p2g_gather(const float4* __restrict__ payload,
                                                 const int* __restrict__ start,
                                                 const int* __restrict__ cnt,
                                                 float* __restrict__ grid)
{
    int t = blockIdx.x;
    int n = cnt[t];
    if (n == 0) return;

    __shared__ float4 buf[256];          // 64-particle staging chunk (4 KB)

    int tid = threadIdx.x;
    int c0 = tid / 6, c1 = tid % 6;      // lanes >= 36: c0 > 5 -> w01 = 0 always
    float fc0 = (float)c0, fc1 = (float)c1;

    float acc[6][4];
#pragma unroll
    for (int k = 0; k < 6; ++k) { acc[k][0] = 0.f; acc[k][1] = 0.f; acc[k][2] = 0.f; acc[k][3] = 0.f; }

    int s0 = start[t];

    for (int pbase = 0; pbase < n; pbase += 64) {
        int cn = n - pbase; if (cn > 64) cn = 64;
        int flat = 4 * cn;
        __syncthreads();
        for (int j = tid; j < flat; j += 64)
            buf[j] = payload[4 * (size_t)(s0 + pbase) + j];
        __syncthreads();

        for (int i = 0; i < cn; ++i) {
            // broadcast reads: all lanes read the same LDS address
            float4 r0 = buf[4*i+0], r1 = buf[4*i+1], r2 = buf[4*i+2], r3 = buf[4*i+3];
            int bits = __float_as_int(r3.w);
            int l0 = bits & 3, l1 = (bits >> 2) & 3, l2 = (bits >> 4) & 3;

            float u0 = r3.x - (fc0 - (float)l0);      // fx0 - d0
            float u1 = r3.y - (fc1 - (float)l1);
            float w01 = bspline_w(u0) * bspline_w(u1);
            float dp0 = -u0 * DXf, dp1 = -u1 * DXf;
            float m0 = r2.y + r0.x * dp0 + r0.y * dp1;
            float m1 = r2.z + r0.w * dp0 + r1.x * dp1;
            float m2 = r2.w + r1.z * dp0 + r1.w * dp1;
            float k2base = r3.z + (float)l2;          // u2 = (fx2 + l2) - c2

#pragma unroll
            for (int c2 = 0; c2 < 6; ++c2) {
                float u2 = k2base - (float)c2;
                float wq = bspline_w(u2);
                float wi = w01 * wq;
                float dp2 = -u2 * DXf;
                acc[c2][0] += wi * (m0 + r0.z * dp2);
                acc[c2][1] += wi * (m1 + r1.y * dp2);
                acc[c2][2] += wi * (m2 + r2.x * dp2);
                acc[c2][3] += wi * P_MASS_F;
            }
        }
    }

    if (tid < 36) {
        int t0 = t / (TPA * TPA), t1 = (t / TPA) % TPA, t2 = t % TPA;
        int g0 = t0 * 4 + c0, g1 = t1 * 4 + c1, org2 = t2 * 4;
        if (g0 < NG && g1 < NG) {
#pragma unroll
            for (int c2 = 0; c2 < 6; ++c2) {
                int g2 = org2 + c2;
                if (g2 >= NG) continue;
                if (acc[c2][3] == 0.f) continue;
                float* gptr = grid + 4 * (((g0 * NG) + g1) * NG + g2);
                atom_add_f32(gptr + 0, acc[c2][0]);
                atom_add_f32(gptr + 1, acc[c2][1]);
                atom_add_f32(gptr + 2, acc[c2][2]);
                atom_add_f32(gptr + 3, acc[c2][3]);
            }
        }
    }
}

// ---------------- fallback P2G: direct global atomics ----------------
__global__ __launch_bounds__(256) void p2g_naive(const float* __restrict__ x,
                                                 const float* __restrict__ v,
                                                 const float* __restrict__ C,
                                                 const float* __restrict__ st,
                                                 float* __restrict__ grid, int n)
{
    int p = blockIdx.x * 256 + threadIdx.x;
    if (p >= n) return;

    float xp0 = x[3*p], xp1 = x[3*p+1], xp2 = x[3*p+2];
    float u0 = xp0 * INV_DX, u1 = xp1 * INV_DX, u2 = xp2 * INV_DX;
    float b0f = floorf(u0 - 0.5f), b1f = floorf(u1 - 0.5f), b2f = floorf(u2 - 0.5f);
    int base0 = (int)b0f, base1 = (int)b1f, base2 = (int)b2f;
    float fx0 = u0 - b0f, fx1 = u1 - b1f, fx2 = u2 - b2f;

    float w[3][3];
    weights_of(fx0, fx1, fx2, w);

    float aff[3][3];
#pragma unroll
    for (int i = 0; i < 3; ++i)
#pragma unroll
        for (int j = 0; j < 3; ++j)
            aff[i][j] = st[9*p + 3*i + j] * AFFINE_SCALE + P_MASS_F * C[9*p + 3*i + j];

    float mv0 = P_MASS_F * v[3*p], mv1 = P_MASS_F * v[3*p+1], mv2 = P_MASS_F * v[3*p+2];

#pragma unroll
    for (int i = 0; i < 3; ++i) {
        float dp0 = ((float)i - fx0) * DXf;
#pragma unroll
        for (int j = 0; j < 3; ++j) {
            float dp1 = ((float)j - fx1) * DXf;
            float wij = w[i][0] * w[j][1];
            float m0 = mv0 + aff[0][0]*dp0 + aff[0][1]*dp1;
            float m1 = mv1 + aff[1][0]*dp0 + aff[1][1]*dp1;
            float m2 = mv2 + aff[2][0]*dp0 + aff[2][1]*dp1;
            int cellij = ((base0 + i) * NG + (base1 + j)) * NG + base2;
#pragma unroll
            for (int k = 0; k < 3; ++k) {
                float dp2 = ((float)k - fx2) * DXf;
                float wi = wij * w[k][2];
                float* cptr = grid + 4 * (cellij + k);
                atom_add_f32(cptr + 0, wi * (m0 + aff[0][2]*dp2));
                atom_add_f32(cptr + 1, wi * (m1 + aff[1][2]*dp2));
                atom_add_f32(cptr + 2, wi * (m2 + aff[2][2]*dp2));
                atom_add_f32(cptr + 3, wi * P_MASS_F);
            }
        }
    }
}

// ---------------- grid: normalize, gravity, boundary ----------------
__global__ __launch_bounds__(256) void grid_kernel(float* __restrict__ grid)
{
    int g = blockIdx.x * 256 + threadIdx.x;
    if (g >= GC) return;
    float4 val = ((const float4*)grid)[g];
    float m = val.w;
    float v0 = 0.f, v1 = 0.f, v2 = 0.f;
    if (m > 0.f) {
        float mm = fmaxf(m, 1e-10f);
        v0 = val.x / mm;
        v1 = val.y / mm + DTf * GRAV_Y;
        v2 = val.z / mm;
    }
    int ci = g >> 12, cj = (g >> 6) & 63, ck = g & 63;
    if ((ci < BOUND && v0 < 0.f) || (ci >= NG - BOUND && v0 > 0.f)) v0 = 0.f;
    if ((cj < BOUND && v1 < 0.f) || (cj >= NG - BOUND && v1 > 0.f)) v1 = 0.f;
    if ((ck < BOUND && v2 < 0.f) || (ck >= NG - BOUND && v2 > 0.f)) v2 = 0.f;
    ((float4*)grid)[g] = make_float4(v0, v1, v2, m);
}

// ---------------- G2P: gather, advect, update C/F ----------------
__global__ __launch_bounds__(256) void g2p_kernel(const float* __restrict__ x,
                                                  const float* __restrict__ F,
                                                  const float* __restrict__ grid,
                                                  float* __restrict__ out_x,
                                                  float* __restrict__ out_v,
                                                  float* __restrict__ out_C,
                                                  float* __restrict__ out_F,
                                                  int n)
{
    int p = blockIdx.x * 256 + threadIdx.x;
    if (p >= n) return;

    float xp0 = x[3*p], xp1 = x[3*p+1], xp2 = x[3*p+2];
    float t0 = xp0 * INV_DX, t1 = xp1 * INV_DX, t2 = xp2 * INV_DX;
    float b0 = floorf(t0 - 0.5f), b1 = floorf(t1 - 0.5f), b2 = floorf(t2 - 0.5f);
    int   base0 = (int)b0, base1 = (int)b1, base2 = (int)b2;
    float fx0 = t0 - b0, fx1 = t1 - b1, fx2 = t2 - b2;

    float w[3][3];
    weights_of(fx0, fx1, fx2, w);

    float vn0 = 0.f, vn1 = 0.f, vn2 = 0.f;
    float Cn[3][3] = {};

#pragma unroll
    for (int i = 0; i < 3; ++i) {
        float dp0 = ((float)i - fx0) * DXf;
#pragma unroll
        for (int j = 0; j < 3; ++j) {
            float dp1 = ((float)j - fx1) * DXf;
            float wij = w[i][0] * w[j][1];
            int cellij = ((base0 + i) * NG + (base1 + j)) * NG + base2;
#pragma unroll
            for (int k = 0; k < 3; ++k) {
                float dp2 = ((float)k - fx2) * DXf;
                float wi = wij * w[k][2];
                float4 gv = ((const float4*)grid)[cellij + k];
                vn0 += wi * gv.x; vn1 += wi * gv.y; vn2 += wi * gv.z;
                float wx = wi * gv.x, wy = wi * gv.y, wz = wi * gv.z;
                Cn[0][0] += wx * dp0; Cn[0][1] += wx * dp1; Cn[0][2] += wx * dp2;
                Cn[1][0] += wy * dp0; Cn[1][1] += wy * dp1; Cn[1][2] += wy * dp2;
                Cn[2][0] += wz * dp0; Cn[2][1] += wz * dp1; Cn[2][2] += wz * dp2;
            }
        }
    }

#pragma unroll
    for (int i = 0; i < 3; ++i)
#pragma unroll
        for (int j = 0; j < 3; ++j)
            Cn[i][j] *= D_INV;

    out_x[3*p]   = xp0 + DTf * vn0;
    out_x[3*p+1] = xp1 + DTf * vn1;
    out_x[3*p+2] = xp2 + DTf * vn2;
    out_v[3*p]   = vn0; out_v[3*p+1] = vn1; out_v[3*p+2] = vn2;

    float Fp[3][3];
#pragma unroll
    for (int i = 0; i < 3; ++i)
#pragma unroll
        for (int j = 0; j < 3; ++j)
            Fp[i][j] = F[9*p + 3*i + j];

#pragma unroll
    for (int i = 0; i < 3; ++i) {
#pragma unroll
        for (int k = 0; k < 3; ++k) {
            float acc = Cn[i][0]*Fp[0][k] + Cn[i][1]*Fp[1][k] + Cn[i][2]*Fp[2][k];
            out_F[9*p + 3*i + k] = Fp[i][k] + DTf * acc;
            out_C[9*p + 3*i + k] = Cn[i][k];
        }
    }
}

extern "C" void kernel_launch(void* const* d_in, const int* in_sizes, int n_in,
                              void* d_out, int out_size, void* d_ws, size_t ws_size,
                              hipStream_t stream)
{
    const float* x  = (const float*)d_in[0];
    const float* v  = (const float*)d_in[1];
    const float* C  = (const float*)d_in[2];
    const float* F  = (const float*)d_in[3];
    const float* st = (const float*)d_in[4];
    int n = in_sizes[0] / 3;

    const size_t grid_bytes = (size_t)GC * 4 * sizeof(float);          // 4 MiB
    const size_t tab_bytes  = (size_t)NT * 3 * sizeof(int);            // 48 KiB
    const bool   use_tiled  = ws_size >= grid_bytes + tab_bytes &&
                              (size_t)out_size >= 22 * (size_t)n;      // payload fits in out[6n..22n]

    char* ws = (char*)d_ws;
    float* grid = (float*)ws;  ws += grid_bytes;
    int* cnt    = (int*)ws;    ws += NT * sizeof(int);
    int* tstart = (int*)ws;    ws += NT * sizeof(int);
    int* cursor = (int*)ws;    ws += NT * sizeof(int);

    float* out  = (float*)d_out;
    float* out_x = out;
    float* out_v = out + 3 * (size_t)n;
    float* out_C = out + 6 * (size_t)n;
    float* out_F = out + 15 * (size_t)n;
    // payload (16 floats/particle) lives in out[6n .. 22n) — dead until g2p overwrites
    float4* payload = (float4*)(out + 6 * (size_t)n);

    int pblocks = (n + 255) / 256;

    if (use_tiled) {
        hipMemsetAsync(grid, 0, grid_bytes + NT * sizeof(int), stream);  // grid + cnt contiguous
        count_kernel<<<pblocks, 256, 0, stream>>>(x, cnt, n);
        scan_kernel<<<1, 256, 0, stream>>>(cnt, tstart, cursor);
        reorder_kernel<<<pblocks, 256, 0, stream>>>(x, v, C, st, cursor, payload, n);
        p2g_gather<<<NT, 64, 0, stream>>>(payload, tstart, cnt, grid);
    } else {
        hipMemsetAsync(grid, 0, grid_bytes, stream);
        p2g_naive<<<pblocks, 256, 0, stream>>>(x, v, C, st, grid, n);
    }

    grid_kernel<<<GC / 256, 256, 0, stream>>>(grid);
    g2p_kernel<<<pblocks, 256, 0, stream>>>(x, F, grid, out_x, out_v, out_C, out_F, n);
}